// Round 15
// baseline (267.793 us; speedup 1.0000x reference)
//
#include <hip/hip_runtime.h>

typedef __bf16 bf16x8 __attribute__((ext_vector_type(8)));
typedef float f32x4 __attribute__((ext_vector_type(4)));

// r15: native bf16 convert (RNE on gfx950; compiler pairs into
// v_cvt_pk_bf16_f32) — replaces 5-op manual bit-math RNE. [A/B vs r14]
__device__ __forceinline__ unsigned short f2bf(float f) {
  return __builtin_bit_cast(unsigned short, (__bf16)f);
}

__device__ __forceinline__ void async16(const void* g, void* l) {
  __builtin_amdgcn_global_load_lds(
      (const __attribute__((address_space(1))) unsigned int*)g,
      (__attribute__((address_space(3))) unsigned int*)l, 16, 0, 0);
}

#define MFMA(a, b, c) __builtin_amdgcn_mfma_f32_16x16x32_bf16((a), (b), (c), 0, 0, 0)

// ---------------------------------------------------------------------------
// pack: fp32 -> bf16 (RNE), vectorized
// ---------------------------------------------------------------------------
__global__ __launch_bounds__(256) void pack_bf16(const float* __restrict__ src,
                                                 unsigned short* __restrict__ dst,
                                                 long n) {
  long i = ((long)blockIdx.x * blockDim.x + threadIdx.x) * 4;
  long stride = (long)gridDim.x * blockDim.x * 4;
  for (; i < n; i += stride) {
    float4 v = *(const float4*)(src + i);
    ushort4 o;
    o.x = f2bf(v.x); o.y = f2bf(v.y); o.z = f2bf(v.z); o.w = f2bf(v.w);
    *(ushort4*)(dst + i) = o;
  }
}

// pack the 3 weight matrices in one launch: grid (1024, 3)
__global__ __launch_bounds__(256) void pack_w3(const float* __restrict__ s0,
                                               const float* __restrict__ s1,
                                               const float* __restrict__ s2,
                                               unsigned short* __restrict__ dst) {
  const float* s = (blockIdx.y == 0) ? s0 : (blockIdx.y == 1) ? s1 : s2;
  long i = ((long)blockIdx.x * 256 + threadIdx.x) * 4;  // covers 1048576 exactly
  float4 v = *(const float4*)(s + i);
  ushort4 o;
  o.x = f2bf(v.x); o.y = f2bf(v.y); o.z = f2bf(v.z); o.w = f2bf(v.w);
  *(ushort4*)(dst + (long)blockIdx.y * 1048576 + i) = o;
}

// ---------------------------------------------------------------------------
// gemm256 (r15 = r14 core + native f2bf; r14 = r8/r12 minus s_setprio).
// 256x256 tile, BK=64, 8 waves (2Mx4N). Software-pipelined fragment reads
// (phase p's ds_reads issued during phase p-1), TWO barriers per K-tile:
//   - mid-tile (end of phase 1): orders phase-0 B-register consumption
//     before phases 2/3 restage the B slots of the current buffer.
//   - tile boundary: vmcnt(4) guarantees A(t+1) landed; barrier makes it
//     block-wide; next tile's phase-0 A fragments prefetched right after.
// Staging: 8 async16/tile, running pointers, clamped tail re-reads.
//  EPI 0: QKV: bf16+bias; Q/K row-major; V written TRANSPOSED (V^T[b][d][s]).
//  EPI 3: scores: bf16 exp(s*scale) weights + per-(row,bn) partial sums.
//  EPI 4: PV: fp32 out / rowsum (psum summed inline).
// ---------------------------------------------------------------------------
template <int EPI>
__global__ __launch_bounds__(512, 1) void gemm256(
    const unsigned short* __restrict__ A, long sAz,
    const unsigned short* __restrict__ B, long sBz,
    int lda, int ldb, int nt,
    float* __restrict__ Cf, long sCz, int ldc, float scale,
    unsigned short* __restrict__ Cq, long sQz, int ldq,
    const float* __restrict__ bq, const float* __restrict__ bk,
    const float* __restrict__ bv, float* __restrict__ psum) {
  extern __shared__ __align__(16) char smem[];
  const int tid = threadIdx.x;
  const int l = tid & 63;
  const int w = tid >> 6;
  const int wm = w >> 2, wn = w & 3;
  int bm = blockIdx.x;
  if ((gridDim.x & 7) == 0) {  // XCD-aware swizzle (bijective: gx % 8 == 0)
    int cpx = gridDim.x >> 3;
    bm = (bm & 7) * cpx + (bm >> 3);
  }
  const int bn = blockIdx.y, bz = blockIdx.z;
  const unsigned short* Ab = A + (long)bz * sAz + (long)bm * 256 * lda;
  const unsigned short* Bb = B + (long)bz * sBz + (long)bn * 256 * ldb;

  const int r0 = tid >> 3;                 // staging row 0..63
  const int sch = (tid & 7) ^ (r0 & 7);    // inverse-swizzled source chunk
  const int l15 = l & 15;
  const int kof = (l >> 4) << 3;           // 0,8,16,24

  const int aslot = wm * 16384;
  const int bslot = 32768 + (wn >> 1) * 16384;
  const int brow0 = (wn & 1) * 64;

  // XOR-folded fragment offset cores: aof[fr][ks] = acore[ks] + fr*2048,
  // bof[fc][ks] = bcore[ks] + fc*2048 (mask bits 4-6 never collide with +2048k)
  const int amask = (l15 & 7) << 4;
  const int acore0 = (aslot + l15 * 128 + kof * 2) ^ amask;
  const int acore1 = (aslot + l15 * 128 + 64 + kof * 2) ^ amask;
  const int bcore0 = (bslot + (brow0 + l15) * 128 + kof * 2) ^ amask;
  const int bcore1 = (bslot + (brow0 + l15) * 128 + 64 + kof * 2) ^ amask;

  // running staging pointers (one per 64-row group), +64 elems per tile
  const unsigned short* pa0 = Ab + (long)r0 * lda + sch * 8;
  const unsigned short* pa1 = pa0 + (long)64 * lda;
  const unsigned short* pa2 = pa0 + (long)128 * lda;
  const unsigned short* pa3 = pa0 + (long)192 * lda;
  const unsigned short* pb0 = Bb + (long)r0 * ldb + sch * 8;
  const unsigned short* pb1 = pb0 + (long)64 * ldb;
  const unsigned short* pb2 = pb0 + (long)128 * ldb;
  const unsigned short* pb3 = pb0 + (long)192 * ldb;

  char* sdst = smem + (tid << 4);  // LDS staging dest base (lane-linear)

  f32x4 acc[8][4] = {};
  bf16x8 bfr[4][2];
  bf16x8 c00, c01, c10, c11;  // current-phase A fragments
  bf16x8 n00, n01, n10, n11;  // next-phase A fragments

#define LDA_F(dst, bb, fr, ks) \
  dst = *(const bf16x8*)(smem + (((ks) ? acore1 : acore0) + (fr)*2048 + (bb)));
#define LDB_F(dst, bb, fc, ks) \
  dst = *(const bf16x8*)(smem + (((ks) ? bcore1 : bcore0) + (fc)*2048 + (bb)));

  // prologue staging: B(0), A(0), B(1)  [12 async16]
  async16(pb0, sdst + 32768);         async16(pb1, sdst + 40960);
  async16(pb2, sdst + 49152);         async16(pb3, sdst + 57344);
  async16(pa0, sdst + 0);             async16(pa1, sdst + 8192);
  async16(pa2, sdst + 16384);         async16(pa3, sdst + 24576);
  async16(pb0 + 64, sdst + 98304);    async16(pb1 + 64, sdst + 106496);
  async16(pb2 + 64, sdst + 114688);   async16(pb3 + 64, sdst + 122880);
  asm volatile("s_waitcnt vmcnt(4)" ::: "memory");
  __builtin_amdgcn_s_barrier();
  pa0 += 64; pa1 += 64; pa2 += 64; pa3 += 64;
  pb0 += 128; pb1 += 128; pb2 += 128; pb3 += 128;

  // initial phase-0 A fragments for tile 0 (buf = 0)
  LDA_F(c00, 0, 0, 0); LDA_F(c01, 0, 0, 1);
  LDA_F(c10, 0, 1, 0); LDA_F(c11, 0, 1, 1);

  for (int t = 0; t < nt; ++t) {
    const int buf = (t & 1) << 16;
    const int nbuf = buf ^ 65536;

    // ---- phase 0: read all B + aN(fr2,3); stage A h0(t+1); MFMA aC(fr0,1)
#pragma unroll
    for (int fc = 0; fc < 4; ++fc) {
      LDB_F(bfr[fc][0], buf, fc, 0);
      LDB_F(bfr[fc][1], buf, fc, 1);
    }
    LDA_F(n00, buf, 2, 0); LDA_F(n01, buf, 2, 1);
    LDA_F(n10, buf, 3, 0); LDA_F(n11, buf, 3, 1);
    async16(pa0, sdst + nbuf);
    async16(pa1, sdst + nbuf + 8192);
#pragma unroll
    for (int fc = 0; fc < 4; ++fc) {
      acc[0][fc] = MFMA(c00, bfr[fc][0], acc[0][fc]);
      acc[0][fc] = MFMA(c01, bfr[fc][1], acc[0][fc]);
      acc[1][fc] = MFMA(c10, bfr[fc][0], acc[1][fc]);
      acc[1][fc] = MFMA(c11, bfr[fc][1], acc[1][fc]);
    }

    // ---- phase 1: read aC(fr4,5); stage A h1(t+1); MFMA aN(fr2,3); mid-bar
    LDA_F(c00, buf, 4, 0); LDA_F(c01, buf, 4, 1);
    LDA_F(c10, buf, 5, 0); LDA_F(c11, buf, 5, 1);
    async16(pa2, sdst + nbuf + 16384);
    async16(pa3, sdst + nbuf + 24576);
#pragma unroll
    for (int fc = 0; fc < 4; ++fc) {
      acc[2][fc] = MFMA(n00, bfr[fc][0], acc[2][fc]);
      acc[2][fc] = MFMA(n01, bfr[fc][1], acc[2][fc]);
      acc[3][fc] = MFMA(n10, bfr[fc][0], acc[3][fc]);
      acc[3][fc] = MFMA(n11, bfr[fc][1], acc[3][fc]);
    }
    __builtin_amdgcn_s_barrier();

    // ---- phase 2: read aN(fr6,7); stage B h0(t+2); MFMA aC(fr4,5)
    LDA_F(n00, buf, 6, 0); LDA_F(n01, buf, 6, 1);
    LDA_F(n10, buf, 7, 0); LDA_F(n11, buf, 7, 1);
    async16(pb0, sdst + buf + 32768);
    async16(pb1, sdst + buf + 40960);
#pragma unroll
    for (int fc = 0; fc < 4; ++fc) {
      acc[4][fc] = MFMA(c00, bfr[fc][0], acc[4][fc]);
      acc[4][fc] = MFMA(c01, bfr[fc][1], acc[4][fc]);
      acc[5][fc] = MFMA(c10, bfr[fc][0], acc[5][fc]);
      acc[5][fc] = MFMA(c11, bfr[fc][1], acc[5][fc]);
    }

    // ---- phase 3: stage B h1(t+2); MFMA aN(fr6,7); vmcnt(4)+barrier
    async16(pb2, sdst + buf + 49152);
    async16(pb3, sdst + buf + 57344);
#pragma unroll
    for (int fc = 0; fc < 4; ++fc) {
      acc[6][fc] = MFMA(n00, bfr[fc][0], acc[6][fc]);
      acc[6][fc] = MFMA(n01, bfr[fc][1], acc[6][fc]);
      acc[7][fc] = MFMA(n10, bfr[fc][0], acc[7][fc]);
      acc[7][fc] = MFMA(n11, bfr[fc][1], acc[7][fc]);
    }
    asm volatile("s_waitcnt vmcnt(4)" ::: "memory");
    __builtin_amdgcn_s_barrier();

    // prefetch next tile's phase-0 A fragments from nbuf (A(t+1) landed)
    LDA_F(c00, nbuf, 0, 0); LDA_F(c01, nbuf, 0, 1);
    LDA_F(c10, nbuf, 1, 0); LDA_F(c11, nbuf, 1, 1);

    // pointer advance with clamp (min(t+1,nt-1)/min(t+2,nt-1) semantics)
    if (t < nt - 2) { pa0 += 64; pa1 += 64; pa2 += 64; pa3 += 64; }
    if (t < nt - 3) { pb0 += 64; pb1 += 64; pb2 += 64; pb3 += 64; }
  }

  asm volatile("s_waitcnt vmcnt(0)" ::: "memory");
  __builtin_amdgcn_s_barrier();

  const int rl = (l >> 4) * 4;  // C/D layout: col=lane&15, row=(lane>>4)*4+reg

  if constexpr (EPI == 0) {
    const int which = (bn * 256) >> 10;      // 0=Q 1=K 2=V
    const int colbase = bn * 256 + wn * 64;
    const float* bias = (which == 0) ? bq : (which == 1) ? bk : bv;
    if (which < 2) {
#pragma unroll
      for (int fr = 0; fr < 8; ++fr)
#pragma unroll
        for (int fc = 0; fc < 4; ++fc) {
          int lc = fc * 16 + l15;
          float bv_ = bias[(colbase + lc) & 1023];
#pragma unroll
          for (int rr = 0; rr < 4; ++rr) {
            int lr = fr * 16 + rl + rr;
            int byte = w * 16384 + lr * 128 + lc * 2;
            byte ^= (lr & 7) << 4;
            *(unsigned short*)(smem + byte) = f2bf(acc[fr][fc][rr] + bv_);
          }
        }
      __syncthreads();
      const long brow = (long)bm * 256;
      const int cw0 = (bn * 256) & 1023;
#pragma unroll
      for (int it = 0; it < 16; ++it) {
        int f = it * 512 + tid;
        int r = f >> 5, ch = f & 31;
        int wv = (r >> 7) * 4 + (ch >> 3);
        int byte = wv * 16384 + (r & 127) * 128 + (ch & 7) * 16;
        byte ^= (r & 7) << 4;
        uint4 val = *(const uint4*)(smem + byte);
        unsigned short* d = Cq + (long)which * 16777216L +
                            (brow + r) * 1024 + cw0 + ch * 8;
        *(uint4*)d = val;
      }
    } else {
      // V: transposed staging [c][r] -> write V^T[b][d][s] coalesced
#pragma unroll
      for (int fr = 0; fr < 8; ++fr)
#pragma unroll
        for (int fc = 0; fc < 4; ++fc) {
          int lc = wn * 64 + fc * 16 + l15;
          float bv_ = bias[(colbase + fc * 16 + l15) & 1023];
#pragma unroll
          for (int rr = 0; rr < 4; ++rr) {
            int r = wm * 128 + fr * 16 + rl + rr;
            int byte = lc * 512 + r * 2;
            byte ^= (lc & 7) << 4;
            *(unsigned short*)(smem + byte) = f2bf(acc[fr][fc][rr] + bv_);
          }
        }
      __syncthreads();
      const long brow = (long)bm * 256;
      const long b = brow >> 11;
      const long s0 = brow & 2047;
      unsigned short* VT = Cq + 2L * 16777216;
#pragma unroll
      for (int it = 0; it < 16; ++it) {
        int f = it * 512 + tid;
        int c = f >> 5, ch = f & 31;
        int byte = (c * 512 + ch * 16) ^ ((c & 7) << 4);
        uint4 val = *(const uint4*)(smem + byte);
        int d = (bn * 256 - 2048) + c;
        unsigned short* dst = VT + b * 2097152 + (long)d * 2048 + s0 + ch * 8;
        *(uint4*)dst = val;
      }
    }
  } else if constexpr (EPI == 3) {
    // scores: w = exp(s*scale) -> bf16 staged; per-row partial sums
    float rs[4];
#pragma unroll
    for (int fr = 0; fr < 8; ++fr) {
      rs[0] = rs[1] = rs[2] = rs[3] = 0.0f;
#pragma unroll
      for (int fc = 0; fc < 4; ++fc) {
        int lc = fc * 16 + l15;
#pragma unroll
        for (int rr = 0; rr < 4; ++rr) {
          float e = __expf(acc[fr][fc][rr] * scale);
          rs[rr] += e;
          int lr = fr * 16 + rl + rr;
          int byte = w * 16384 + lr * 128 + lc * 2;
          byte ^= (lr & 7) << 4;
          *(unsigned short*)(smem + byte) = f2bf(e);
        }
      }
#pragma unroll
      for (int rr = 0; rr < 4; ++rr) {
        float v = rs[rr];
#pragma unroll
        for (int o = 1; o < 16; o <<= 1) v += __shfl_xor(v, o);
        if (l15 == 0) {
          int row = wm * 128 + fr * 16 + rl + rr;
          *(float*)(smem + 131072 + (wn * 256 + row) * 4) = v;
        }
      }
    }
    __syncthreads();
    const long brow = (long)bm * 256;
#pragma unroll
    for (int it = 0; it < 16; ++it) {
      int f = it * 512 + tid;
      int r = f >> 5, ch = f & 31;
      int wv = (r >> 7) * 4 + (ch >> 3);
      int byte = wv * 16384 + (r & 127) * 128 + (ch & 7) * 16;
      byte ^= (r & 7) << 4;
      uint4 val = *(const uint4*)(smem + byte);
      unsigned short* d = Cq + (long)bz * sQz + (brow + r) * ldq + bn * 256 + ch * 8;
      *(uint4*)d = val;
    }
    if (tid < 256) {
      float s4 = *(const float*)(smem + 131072 + tid * 4) +
                 *(const float*)(smem + 131072 + 1024 + tid * 4) +
                 *(const float*)(smem + 131072 + 2048 + tid * 4) +
                 *(const float*)(smem + 131072 + 3072 + tid * 4);
      psum[(((long)bz * 2048) + brow + tid) * 8 + bn] = s4;
    }
  } else {  // EPI == 4: PV, normalize by inline psum row-sum
    float* C = Cf + (long)bz * sCz;
    const long grbase = (long)bm * 256 + wm * 128;
    const int gcbase = bn * 256 + wn * 64;
#pragma unroll
    for (int fr = 0; fr < 8; ++fr)
#pragma unroll
      for (int rr = 0; rr < 4; ++rr) {
        long gr = grbase + fr * 16 + rl + rr;
        const float* pp = psum + (((long)bz * 2048) + gr) * 8;
        float4 s0 = *(const float4*)pp;
        float4 s1 = *(const float4*)(pp + 4);
        float inv = 1.0f / (s0.x + s0.y + s0.z + s0.w +
                            s1.x + s1.y + s1.z + s1.w);
#pragma unroll
        for (int fc = 0; fc < 4; ++fc)
          C[gr * ldc + gcbase + fc * 16 + l15] = acc[fr][fc][rr] * inv;
      }
  }
#undef LDA_F
#undef LDB_F
}

__global__ void sentinel_kernel(float* out, float v) { out[0] = v; }

// ---------------------------------------------------------------------------
extern "C" void kernel_launch(void* const* d_in, const int* in_sizes, int n_in,
                              void* d_out, int out_size, void* d_ws, size_t ws_size,
                              hipStream_t stream) {
  const float* x  = (const float*)d_in[0];
  const float* Wq = (const float*)d_in[1];
  const float* bq = (const float*)d_in[2];
  const float* Wk = (const float*)d_in[3];
  const float* bk = (const float*)d_in[4];
  const float* Wv = (const float*)d_in[5];
  const float* bv = (const float*)d_in[6];
  float* out = (float*)d_out;

  (void)hipFuncSetAttribute((const void*)gemm256<0>,
      hipFuncAttributeMaxDynamicSharedMemorySize, 135168);
  (void)hipFuncSetAttribute((const void*)gemm256<3>,
      hipFuncAttributeMaxDynamicSharedMemorySize, 135168);
  (void)hipFuncSetAttribute((const void*)gemm256<4>,
      hipFuncAttributeMaxDynamicSharedMemorySize, 135168);

  // Tiers (chosen by ws_size -> constant across calls):
  //  BIG2 (>=208207872): single-shot z=8.
  //    qkv[0,96M): Q[0,32M) K[32,64) VT[64,96)
  //    xb[96,128M) wb[128,134.2M) (dead after QKV)  wt[134.2M,198.2M)
  //    psum[198.2M,+512K)
  //  SMALL2 (>=140509184): 4 passes x z=2; wt(16M)+psum inside dead xb.
  const size_t NEED_BIG2 = 208207872;
  const size_t NEED_SM2  = 140509184;
  if (ws_size < NEED_SM2) {
    sentinel_kernel<<<1, 1, 0, stream>>>(out, (float)ws_size);
    return;
  }
  const bool big = (ws_size >= NEED_BIG2);
  char* ws = (char*)d_ws;
  unsigned short* qkv = (unsigned short*)(ws);
  unsigned short* xb  = (unsigned short*)(ws + 100663296);
  unsigned short* wb  = (unsigned short*)(ws + 134217728);
  unsigned short* wt  = big ? (unsigned short*)(ws + 140509184)
                            : (unsigned short*)(ws + 100663296);
  float* psum = big ? (float*)(ws + 207618048) : (float*)(ws + 117440512);

  const float scale = 0.03125f;  // 1/sqrt(1024)

  pack_bf16<<<dim3(4096), dim3(256), 0, stream>>>(x, xb, 16777216L);
  pack_w3<<<dim3(1024, 3), dim3(256), 0, stream>>>(Wq, Wk, Wv, wb);

  // QKV projection: [16384,1024] x [3072,1024]^T -> Q,K row-major + V^T
  gemm256<0><<<dim3(64, 12, 1), dim3(512), 135168, stream>>>(
      xb, 0L, wb, 0L, 1024, 1024, 16,
      nullptr, 0L, 0, 1.0f, qkv, 0L, 1024, bq, bk, bv, nullptr);

  const int bpp = big ? 8 : 2;
  const int npasses = 8 / bpp;
  for (int p = 0; p < npasses; ++p) {
    long b0 = (long)p * bpp;
    long boff = b0 * 2048 * 1024;
    // scores: exp(QK^T * scale) -> bf16 weights wt + psum partials
    gemm256<3><<<dim3(8, 8, bpp), dim3(512), 135168, stream>>>(
        qkv + boff, 2048L * 1024, qkv + 16777216 + boff, 2048L * 1024,
        1024, 1024, 16,
        nullptr, 0L, 0, scale, wt, 2048L * 2048, 2048,
        nullptr, nullptr, nullptr, psum);

    // out = (wt @ V^T-rows) / rowsum : fp32
    gemm256<4><<<dim3(8, 4, bpp), dim3(512), 135168, stream>>>(
        wt, 2048L * 2048, qkv + 2L * 16777216 + b0 * 2097152, 2097152L,
        2048, 2048, 32,
        out + boff, 2048L * 1024, 1024, 1.0f, nullptr, 0L, 0,
        nullptr, nullptr, nullptr, psum);
  }
}

// Round 16
// 262.858 us; speedup vs baseline: 1.0188x; 1.0188x over previous
//
#include <hip/hip_runtime.h>

typedef __bf16 bf16x8 __attribute__((ext_vector_type(8)));
typedef float f32x4 __attribute__((ext_vector_type(4)));

// native bf16 convert (RNE on gfx950; compiler pairs into v_cvt_pk_bf16_f32)
__device__ __forceinline__ unsigned short f2bf(float f) {
  return __builtin_bit_cast(unsigned short, (__bf16)f);
}

__device__ __forceinline__ void async16(const void* g, void* l) {
  __builtin_amdgcn_global_load_lds(
      (const __attribute__((address_space(1))) unsigned int*)g,
      (__attribute__((address_space(3))) unsigned int*)l, 16, 0, 0);
}

#define MFMA(a, b, c) __builtin_amdgcn_mfma_f32_16x16x32_bf16((a), (b), (c), 0, 0, 0)

// ---------------------------------------------------------------------------
// pack_all (r16): single launch packs x AND the 3 weight matrices.
// blocks [0,4096): x (grid-stride, 4 sweeps of 4.19M elems = 16.7M)
// blocks [4096,7168): Wq|Wk|Wv (3 x 1024 blocks, one 4-elem chunk each)
// ---------------------------------------------------------------------------
__global__ __launch_bounds__(256) void pack_all(
    const float* __restrict__ x,
    const float* __restrict__ w0, const float* __restrict__ w1,
    const float* __restrict__ w2,
    unsigned short* __restrict__ xb, unsigned short* __restrict__ wb) {
  int b = blockIdx.x;
  if (b < 4096) {
    long i = ((long)b * 256 + threadIdx.x) * 4;
    const long stride = 4096L * 256 * 4;
    for (; i < 16777216L; i += stride) {
      float4 v = *(const float4*)(x + i);
      ushort4 o;
      o.x = f2bf(v.x); o.y = f2bf(v.y); o.z = f2bf(v.z); o.w = f2bf(v.w);
      *(ushort4*)(xb + i) = o;
    }
  } else {
    int wi = (b - 4096) >> 10;            // 0..2
    int bb = (b - 4096) & 1023;
    const float* s = (wi == 0) ? w0 : (wi == 1) ? w1 : w2;
    long i = ((long)bb * 256 + threadIdx.x) * 4;  // covers 1048576 exactly
    float4 v = *(const float4*)(s + i);
    ushort4 o;
    o.x = f2bf(v.x); o.y = f2bf(v.y); o.z = f2bf(v.z); o.w = f2bf(v.w);
    *(ushort4*)(wb + (long)wi * 1048576 + i) = o;
  }
}

// ---------------------------------------------------------------------------
// gemm256 (r16 = r15 core, unchanged): C[M,N] = A[M,K] * B[N,K]^T.
// 256x256 tile, BK=64, 8 waves (2Mx4N). Software-pipelined fragment reads
// (phase p's ds_reads issued during phase p-1), TWO barriers per K-tile:
//   - mid-tile (end of phase 1): orders phase-0 B-register consumption
//     before phases 2/3 restage the B slots of the current buffer.
//   - tile boundary: vmcnt(4) guarantees A(t+1) landed; barrier makes it
//     block-wide; next tile's phase-0 A fragments prefetched right after.
// No s_setprio (hurts near-lockstep GEMM, m190 + r14 A/B: −5.5 us QKV).
// Staging: 8 async16/tile, running pointers, clamped tail re-reads.
//  EPI 0: QKV: bf16+bias; Q/K row-major; V written TRANSPOSED (V^T[b][d][s]).
//  EPI 3: scores: bf16 exp(s*scale) weights + per-(row,bn) partial sums.
//  EPI 4: PV: fp32 out / rowsum (psum summed inline).
// Session plateau note: five schedule variants converge at MfmaUtil 42-46%;
// the documented path past this (m201 exact lockstep port) underperformed or
// broke in three reconstruction attempts (r5, r9-r11). Structure is
// issue/dependency-bound, not MFMA- or HBM-pipe-bound.
// ---------------------------------------------------------------------------
template <int EPI>
__global__ __launch_bounds__(512, 1) void gemm256(
    const unsigned short* __restrict__ A, long sAz,
    const unsigned short* __restrict__ B, long sBz,
    int lda, int ldb, int nt,
    float* __restrict__ Cf, long sCz, int ldc, float scale,
    unsigned short* __restrict__ Cq, long sQz, int ldq,
    const float* __restrict__ bq, const float* __restrict__ bk,
    const float* __restrict__ bv, float* __restrict__ psum) {
  extern __shared__ __align__(16) char smem[];
  const int tid = threadIdx.x;
  const int l = tid & 63;
  const int w = tid >> 6;
  const int wm = w >> 2, wn = w & 3;
  int bm = blockIdx.x;
  if ((gridDim.x & 7) == 0) {  // XCD-aware swizzle (bijective: gx % 8 == 0)
    int cpx = gridDim.x >> 3;
    bm = (bm & 7) * cpx + (bm >> 3);
  }
  const int bn = blockIdx.y, bz = blockIdx.z;
  const unsigned short* Ab = A + (long)bz * sAz + (long)bm * 256 * lda;
  const unsigned short* Bb = B + (long)bz * sBz + (long)bn * 256 * ldb;

  const int r0 = tid >> 3;                 // staging row 0..63
  const int sch = (tid & 7) ^ (r0 & 7);    // inverse-swizzled source chunk
  const int l15 = l & 15;
  const int kof = (l >> 4) << 3;           // 0,8,16,24

  const int aslot = wm * 16384;
  const int bslot = 32768 + (wn >> 1) * 16384;
  const int brow0 = (wn & 1) * 64;

  // XOR-folded fragment offset cores: aof[fr][ks] = acore[ks] + fr*2048,
  // bof[fc][ks] = bcore[ks] + fc*2048 (mask bits 4-6 never collide with +2048k)
  const int amask = (l15 & 7) << 4;
  const int acore0 = (aslot + l15 * 128 + kof * 2) ^ amask;
  const int acore1 = (aslot + l15 * 128 + 64 + kof * 2) ^ amask;
  const int bcore0 = (bslot + (brow0 + l15) * 128 + kof * 2) ^ amask;
  const int bcore1 = (bslot + (brow0 + l15) * 128 + 64 + kof * 2) ^ amask;

  // running staging pointers (one per 64-row group), +64 elems per tile
  const unsigned short* pa0 = Ab + (long)r0 * lda + sch * 8;
  const unsigned short* pa1 = pa0 + (long)64 * lda;
  const unsigned short* pa2 = pa0 + (long)128 * lda;
  const unsigned short* pa3 = pa0 + (long)192 * lda;
  const unsigned short* pb0 = Bb + (long)r0 * ldb + sch * 8;
  const unsigned short* pb1 = pb0 + (long)64 * ldb;
  const unsigned short* pb2 = pb0 + (long)128 * ldb;
  const unsigned short* pb3 = pb0 + (long)192 * ldb;

  char* sdst = smem + (tid << 4);  // LDS staging dest base (lane-linear)

  f32x4 acc[8][4] = {};
  bf16x8 bfr[4][2];
  bf16x8 c00, c01, c10, c11;  // current-phase A fragments
  bf16x8 n00, n01, n10, n11;  // next-phase A fragments

#define LDA_F(dst, bb, fr, ks) \
  dst = *(const bf16x8*)(smem + (((ks) ? acore1 : acore0) + (fr)*2048 + (bb)));
#define LDB_F(dst, bb, fc, ks) \
  dst = *(const bf16x8*)(smem + (((ks) ? bcore1 : bcore0) + (fc)*2048 + (bb)));

  // prologue staging: B(0), A(0), B(1)  [12 async16]
  async16(pb0, sdst + 32768);         async16(pb1, sdst + 40960);
  async16(pb2, sdst + 49152);         async16(pb3, sdst + 57344);
  async16(pa0, sdst + 0);             async16(pa1, sdst + 8192);
  async16(pa2, sdst + 16384);         async16(pa3, sdst + 24576);
  async16(pb0 + 64, sdst + 98304);    async16(pb1 + 64, sdst + 106496);
  async16(pb2 + 64, sdst + 114688);   async16(pb3 + 64, sdst + 122880);
  asm volatile("s_waitcnt vmcnt(4)" ::: "memory");
  __builtin_amdgcn_s_barrier();
  pa0 += 64; pa1 += 64; pa2 += 64; pa3 += 64;
  pb0 += 128; pb1 += 128; pb2 += 128; pb3 += 128;

  // initial phase-0 A fragments for tile 0 (buf = 0)
  LDA_F(c00, 0, 0, 0); LDA_F(c01, 0, 0, 1);
  LDA_F(c10, 0, 1, 0); LDA_F(c11, 0, 1, 1);

  for (int t = 0; t < nt; ++t) {
    const int buf = (t & 1) << 16;
    const int nbuf = buf ^ 65536;

    // ---- phase 0: read all B + aN(fr2,3); stage A h0(t+1); MFMA aC(fr0,1)
#pragma unroll
    for (int fc = 0; fc < 4; ++fc) {
      LDB_F(bfr[fc][0], buf, fc, 0);
      LDB_F(bfr[fc][1], buf, fc, 1);
    }
    LDA_F(n00, buf, 2, 0); LDA_F(n01, buf, 2, 1);
    LDA_F(n10, buf, 3, 0); LDA_F(n11, buf, 3, 1);
    async16(pa0, sdst + nbuf);
    async16(pa1, sdst + nbuf + 8192);
#pragma unroll
    for (int fc = 0; fc < 4; ++fc) {
      acc[0][fc] = MFMA(c00, bfr[fc][0], acc[0][fc]);
      acc[0][fc] = MFMA(c01, bfr[fc][1], acc[0][fc]);
      acc[1][fc] = MFMA(c10, bfr[fc][0], acc[1][fc]);
      acc[1][fc] = MFMA(c11, bfr[fc][1], acc[1][fc]);
    }

    // ---- phase 1: read aC(fr4,5); stage A h1(t+1); MFMA aN(fr2,3); mid-bar
    LDA_F(c00, buf, 4, 0); LDA_F(c01, buf, 4, 1);
    LDA_F(c10, buf, 5, 0); LDA_F(c11, buf, 5, 1);
    async16(pa2, sdst + nbuf + 16384);
    async16(pa3, sdst + nbuf + 24576);
#pragma unroll
    for (int fc = 0; fc < 4; ++fc) {
      acc[2][fc] = MFMA(n00, bfr[fc][0], acc[2][fc]);
      acc[2][fc] = MFMA(n01, bfr[fc][1], acc[2][fc]);
      acc[3][fc] = MFMA(n10, bfr[fc][0], acc[3][fc]);
      acc[3][fc] = MFMA(n11, bfr[fc][1], acc[3][fc]);
    }
    __builtin_amdgcn_s_barrier();

    // ---- phase 2: read aN(fr6,7); stage B h0(t+2); MFMA aC(fr4,5)
    LDA_F(n00, buf, 6, 0); LDA_F(n01, buf, 6, 1);
    LDA_F(n10, buf, 7, 0); LDA_F(n11, buf, 7, 1);
    async16(pb0, sdst + buf + 32768);
    async16(pb1, sdst + buf + 40960);
#pragma unroll
    for (int fc = 0; fc < 4; ++fc) {
      acc[4][fc] = MFMA(c00, bfr[fc][0], acc[4][fc]);
      acc[4][fc] = MFMA(c01, bfr[fc][1], acc[4][fc]);
      acc[5][fc] = MFMA(c10, bfr[fc][0], acc[5][fc]);
      acc[5][fc] = MFMA(c11, bfr[fc][1], acc[5][fc]);
    }

    // ---- phase 3: stage B h1(t+2); MFMA aN(fr6,7); vmcnt(4)+barrier
    async16(pb2, sdst + buf + 49152);
    async16(pb3, sdst + buf + 57344);
#pragma unroll
    for (int fc = 0; fc < 4; ++fc) {
      acc[6][fc] = MFMA(n00, bfr[fc][0], acc[6][fc]);
      acc[6][fc] = MFMA(n01, bfr[fc][1], acc[6][fc]);
      acc[7][fc] = MFMA(n10, bfr[fc][0], acc[7][fc]);
      acc[7][fc] = MFMA(n11, bfr[fc][1], acc[7][fc]);
    }
    asm volatile("s_waitcnt vmcnt(4)" ::: "memory");
    __builtin_amdgcn_s_barrier();

    // prefetch next tile's phase-0 A fragments from nbuf (A(t+1) landed)
    LDA_F(c00, nbuf, 0, 0); LDA_F(c01, nbuf, 0, 1);
    LDA_F(c10, nbuf, 1, 0); LDA_F(c11, nbuf, 1, 1);

    // pointer advance with clamp (min(t+1,nt-1)/min(t+2,nt-1) semantics)
    if (t < nt - 2) { pa0 += 64; pa1 += 64; pa2 += 64; pa3 += 64; }
    if (t < nt - 3) { pb0 += 64; pb1 += 64; pb2 += 64; pb3 += 64; }
  }

  asm volatile("s_waitcnt vmcnt(0)" ::: "memory");
  __builtin_amdgcn_s_barrier();

  const int rl = (l >> 4) * 4;  // C/D layout: col=lane&15, row=(lane>>4)*4+reg

  if constexpr (EPI == 0) {
    const int which = (bn * 256) >> 10;      // 0=Q 1=K 2=V
    const int colbase = bn * 256 + wn * 64;
    const float* bias = (which == 0) ? bq : (which == 1) ? bk : bv;
    if (which < 2) {
#pragma unroll
      for (int fr = 0; fr < 8; ++fr)
#pragma unroll
        for (int fc = 0; fc < 4; ++fc) {
          int lc = fc * 16 + l15;
          float bv_ = bias[(colbase + lc) & 1023];
#pragma unroll
          for (int rr = 0; rr < 4; ++rr) {
            int lr = fr * 16 + rl + rr;
            int byte = w * 16384 + lr * 128 + lc * 2;
            byte ^= (lr & 7) << 4;
            *(unsigned short*)(smem + byte) = f2bf(acc[fr][fc][rr] + bv_);
          }
        }
      __syncthreads();
      const long brow = (long)bm * 256;
      const int cw0 = (bn * 256) & 1023;
#pragma unroll
      for (int it = 0; it < 16; ++it) {
        int f = it * 512 + tid;
        int r = f >> 5, ch = f & 31;
        int wv = (r >> 7) * 4 + (ch >> 3);
        int byte = wv * 16384 + (r & 127) * 128 + (ch & 7) * 16;
        byte ^= (r & 7) << 4;
        uint4 val = *(const uint4*)(smem + byte);
        unsigned short* d = Cq + (long)which * 16777216L +
                            (brow + r) * 1024 + cw0 + ch * 8;
        *(uint4*)d = val;
      }
    } else {
      // V: transposed staging [c][r] -> write V^T[b][d][s] coalesced
#pragma unroll
      for (int fr = 0; fr < 8; ++fr)
#pragma unroll
        for (int fc = 0; fc < 4; ++fc) {
          int lc = wn * 64 + fc * 16 + l15;
          float bv_ = bias[(colbase + fc * 16 + l15) & 1023];
#pragma unroll
          for (int rr = 0; rr < 4; ++rr) {
            int r = wm * 128 + fr * 16 + rl + rr;
            int byte = lc * 512 + r * 2;
            byte ^= (lc & 7) << 4;
            *(unsigned short*)(smem + byte) = f2bf(acc[fr][fc][rr] + bv_);
          }
        }
      __syncthreads();
      const long brow = (long)bm * 256;
      const long b = brow >> 11;
      const long s0 = brow & 2047;
      unsigned short* VT = Cq + 2L * 16777216;
#pragma unroll
      for (int it = 0; it < 16; ++it) {
        int f = it * 512 + tid;
        int c = f >> 5, ch = f & 31;
        int byte = (c * 512 + ch * 16) ^ ((c & 7) << 4);
        uint4 val = *(const uint4*)(smem + byte);
        int d = (bn * 256 - 2048) + c;
        unsigned short* dst = VT + b * 2097152 + (long)d * 2048 + s0 + ch * 8;
        *(uint4*)dst = val;
      }
    }
  } else if constexpr (EPI == 3) {
    // scores: w = exp(s*scale) -> bf16 staged; per-row partial sums
    float rs[4];
#pragma unroll
    for (int fr = 0; fr < 8; ++fr) {
      rs[0] = rs[1] = rs[2] = rs[3] = 0.0f;
#pragma unroll
      for (int fc = 0; fc < 4; ++fc) {
        int lc = fc * 16 + l15;
#pragma unroll
        for (int rr = 0; rr < 4; ++rr) {
          float e = __expf(acc[fr][fc][rr] * scale);
          rs[rr] += e;
          int lr = fr * 16 + rl + rr;
          int byte = w * 16384 + lr * 128 + lc * 2;
          byte ^= (lr & 7) << 4;
          *(unsigned short*)(smem + byte) = f2bf(e);
        }
      }
#pragma unroll
      for (int rr = 0; rr < 4; ++rr) {
        float v = rs[rr];
#pragma unroll
        for (int o = 1; o < 16; o <<= 1) v += __shfl_xor(v, o);
        if (l15 == 0) {
          int row = wm * 128 + fr * 16 + rl + rr;
          *(float*)(smem + 131072 + (wn * 256 + row) * 4) = v;
        }
      }
    }
    __syncthreads();
    const long brow = (long)bm * 256;
#pragma unroll
    for (int it = 0; it < 16; ++it) {
      int f = it * 512 + tid;
      int r = f >> 5, ch = f & 31;
      int wv = (r >> 7) * 4 + (ch >> 3);
      int byte = wv * 16384 + (r & 127) * 128 + (ch & 7) * 16;
      byte ^= (r & 7) << 4;
      uint4 val = *(const uint4*)(smem + byte);
      unsigned short* d = Cq + (long)bz * sQz + (brow + r) * ldq + bn * 256 + ch * 8;
      *(uint4*)d = val;
    }
    if (tid < 256) {
      float s4 = *(const float*)(smem + 131072 + tid * 4) +
                 *(const float*)(smem + 131072 + 1024 + tid * 4) +
                 *(const float*)(smem + 131072 + 2048 + tid * 4) +
                 *(const float*)(smem + 131072 + 3072 + tid * 4);
      psum[(((long)bz * 2048) + brow + tid) * 8 + bn] = s4;
    }
  } else {  // EPI == 4: PV, normalize by inline psum row-sum
    float* C = Cf + (long)bz * sCz;
    const long grbase = (long)bm * 256 + wm * 128;
    const int gcbase = bn * 256 + wn * 64;
#pragma unroll
    for (int fr = 0; fr < 8; ++fr)
#pragma unroll
      for (int rr = 0; rr < 4; ++rr) {
        long gr = grbase + fr * 16 + rl + rr;
        const float* pp = psum + (((long)bz * 2048) + gr) * 8;
        float4 s0 = *(const float4*)pp;
        float4 s1 = *(const float4*)(pp + 4);
        float inv = 1.0f / (s0.x + s0.y + s0.z + s0.w +
                            s1.x + s1.y + s1.z + s1.w);
#pragma unroll
        for (int fc = 0; fc < 4; ++fc)
          C[gr * ldc + gcbase + fc * 16 + l15] = acc[fr][fc][rr] * inv;
      }
  }
#undef LDA_F
#undef LDB_F
}

__global__ void sentinel_kernel(float* out, float v) { out[0] = v; }

// ---------------------------------------------------------------------------
extern "C" void kernel_launch(void* const* d_in, const int* in_sizes, int n_in,
                              void* d_out, int out_size, void* d_ws, size_t ws_size,
                              hipStream_t stream) {
  const float* x  = (const float*)d_in[0];
  const float* Wq = (const float*)d_in[1];
  const float* bq = (const float*)d_in[2];
  const float* Wk = (const float*)d_in[3];
  const float* bk = (const float*)d_in[4];
  const float* Wv = (const float*)d_in[5];
  const float* bv = (const float*)d_in[6];
  float* out = (float*)d_out;

  (void)hipFuncSetAttribute((const void*)gemm256<0>,
      hipFuncAttributeMaxDynamicSharedMemorySize, 135168);
  (void)hipFuncSetAttribute((const void*)gemm256<3>,
      hipFuncAttributeMaxDynamicSharedMemorySize, 135168);
  (void)hipFuncSetAttribute((const void*)gemm256<4>,
      hipFuncAttributeMaxDynamicSharedMemorySize, 135168);

  // Tiers (chosen by ws_size -> constant across calls):
  //  BIG2 (>=208207872): single-shot z=8.
  //    qkv[0,96M): Q[0,32M) K[32,64) VT[64,96)
  //    xb[96,128M) wb[128,134.2M) (dead after QKV)  wt[134.2M,198.2M)
  //    psum[198.2M,+512K)
  //  SMALL2 (>=140509184): 4 passes x z=2; wt(16M)+psum inside dead xb.
  const size_t NEED_BIG2 = 208207872;
  const size_t NEED_SM2  = 140509184;
  if (ws_size < NEED_SM2) {
    sentinel_kernel<<<1, 1, 0, stream>>>(out, (float)ws_size);
    return;
  }
  const bool big = (ws_size >= NEED_BIG2);
  char* ws = (char*)d_ws;
  unsigned short* qkv = (unsigned short*)(ws);
  unsigned short* xb  = (unsigned short*)(ws + 100663296);
  unsigned short* wb  = (unsigned short*)(ws + 134217728);
  unsigned short* wt  = big ? (unsigned short*)(ws + 140509184)
                            : (unsigned short*)(ws + 100663296);
  float* psum = big ? (float*)(ws + 207618048) : (float*)(ws + 117440512);

  const float scale = 0.03125f;  // 1/sqrt(1024)

  // single merged pack launch (x + Wq/Wk/Wv)
  pack_all<<<dim3(7168), dim3(256), 0, stream>>>(x, Wq, Wk, Wv, xb, wb);

  // QKV projection: [16384,1024] x [3072,1024]^T -> Q,K row-major + V^T
  gemm256<0><<<dim3(64, 12, 1), dim3(512), 135168, stream>>>(
      xb, 0L, wb, 0L, 1024, 1024, 16,
      nullptr, 0L, 0, 1.0f, qkv, 0L, 1024, bq, bk, bv, nullptr);

  const int bpp = big ? 8 : 2;
  const int npasses = 8 / bpp;
  for (int p = 0; p < npasses; ++p) {
    long b0 = (long)p * bpp;
    long boff = b0 * 2048 * 1024;
    // scores: exp(QK^T * scale) -> bf16 weights wt + psum partials
    gemm256<3><<<dim3(8, 8, bpp), dim3(512), 135168, stream>>>(
        qkv + boff, 2048L * 1024, qkv + 16777216 + boff, 2048L * 1024,
        1024, 1024, 16,
        nullptr, 0L, 0, scale, wt, 2048L * 2048, 2048,
        nullptr, nullptr, nullptr, psum);

    // out = (wt @ V^T-rows) / rowsum : fp32
    gemm256<4><<<dim3(8, 4, bpp), dim3(512), 135168, stream>>>(
        wt, 2048L * 2048, qkv + 2L * 16777216 + b0 * 2097152, 2097152L,
        2048, 2048, 32,
        out + boff, 2048L * 1024, 1024, 1.0f, nullptr, 0L, 0,
        nullptr, nullptr, nullptr, psum);
  }
}